// Round 2
// baseline (1354.728 us; speedup 1.0000x reference)
//
#include <hip/hip_runtime.h>

// Problem constants (from reference)
#define VOCAB 32000
#define NNZ   801
#define NNZ_FULL 768          // 12 * 64 full wave-iterations
#define NNZ_TAIL 33           // 801 - 768
#define NROWS 8192            // B*T = 4*2048
#define ROWS_PER_BLOCK 4      // 4 waves of 64 per 256-thread block

__device__ __forceinline__ float warp_reduce_add_f(float v) {
    #pragma unroll
    for (int off = 32; off > 0; off >>= 1) v += __shfl_down(v, off, 64);
    return v;
}

__global__ __launch_bounds__(256) void wordsmooth_main(
        const float* __restrict__ logp,        // [NROWS, VOCAB]
        const float* __restrict__ mask,        // [NROWS]
        const float* __restrict__ sim_values,  // [VOCAB, NNZ]
        const float* __restrict__ idf_values,  // [VOCAB, NNZ]
        const int*   __restrict__ target,      // [NROWS]
        const int*   __restrict__ sim_cols,    // [VOCAB, NNZ]
        double*      __restrict__ partials)    // [3 * NROWS] in ws
{
    const int lane = threadIdx.x & 63;
    const int wave = threadIdx.x >> 6;
    const int row  = blockIdx.x * ROWS_PER_BLOCK + wave;   // n in [0, NROWS)
    if (row >= NROWS) return;

    const int trow = target[row];
    const float* __restrict__ lp_row = logp + (size_t)row * VOCAB;
    const float* __restrict__ sv_p = sim_values + (size_t)trow * NNZ;
    const float* __restrict__ iv_p = idf_values + (size_t)trow * NNZ;
    const int*   __restrict__ sc_p = sim_cols   + (size_t)trow * NNZ;

    // vals = exp(exp((s - 1 - TAU*RARE*idf)/TAU)/TAU); TAU=0.8, RARE=1.0
    // smooth_row = -sum(g*vals)/sum(vals)   [sim row-normalization folded in]
    const float TAU_INV  = 1.25f;    // 1/0.8
    const float TAU_RARE = 0.8f;     // TAU*RARE

    float s_v = 0.0f, s_gv = 0.0f;

    // 12 full iterations, no bounds check -> compiler can unroll & batch loads
    #pragma unroll 4
    for (int j = lane; j < NNZ_FULL; j += 64) {
        float sv = __builtin_nontemporal_load(sv_p + j);
        float iv = __builtin_nontemporal_load(iv_p + j);
        int   c  = __builtin_nontemporal_load(sc_p + j);
        float x   = (sv - 1.0f - TAU_RARE * iv) * TAU_INV;
        float val = __expf(__expf(x) * TAU_INV);
        float g   = lp_row[c];        // random gather within this logp row
        s_v  += val;
        s_gv += g * val;
    }
    // tail: lanes 0..32 handle j = 768..800
    if (lane < NNZ_TAIL) {
        int j = NNZ_FULL + lane;
        float sv = __builtin_nontemporal_load(sv_p + j);
        float iv = __builtin_nontemporal_load(iv_p + j);
        int   c  = __builtin_nontemporal_load(sc_p + j);
        float x   = (sv - 1.0f - TAU_RARE * iv) * TAU_INV;
        float val = __expf(__expf(x) * TAU_INV);
        float g   = lp_row[c];
        s_v  += val;
        s_gv += g * val;
    }

    s_v  = warp_reduce_add_f(s_v);
    s_gv = warp_reduce_add_f(s_gv);

    if (lane == 0) {
        float m = mask[row];
        partials[row]             = (double)(-s_gv / s_v);       // smooth partial
        partials[NROWS + row]     = (double)(-lp_row[trow] * m); // ml partial
        partials[2 * NROWS + row] = (double)m;                   // denom partial
    }
}

__global__ __launch_bounds__(256) void wordsmooth_finalize(
        const double* __restrict__ partials, float* __restrict__ out)
{
    double s = 0.0, ml = 0.0, dn = 0.0;
    for (int i = threadIdx.x; i < NROWS; i += 256) {
        s  += partials[i];
        ml += partials[NROWS + i];
        dn += partials[2 * NROWS + i];
    }
    #pragma unroll
    for (int off = 32; off > 0; off >>= 1) {
        s  += __shfl_down(s,  off, 64);
        ml += __shfl_down(ml, off, 64);
        dn += __shfl_down(dn, off, 64);
    }
    __shared__ double sh[3][4];
    const int lane = threadIdx.x & 63;
    const int wave = threadIdx.x >> 6;
    if (lane == 0) { sh[0][wave] = s; sh[1][wave] = ml; sh[2][wave] = dn; }
    __syncthreads();
    if (threadIdx.x == 0) {
        double S = 0.0, M = 0.0, D = 0.0;
        #pragma unroll
        for (int w = 0; w < 4; ++w) { S += sh[0][w]; M += sh[1][w]; D += sh[2][w]; }
        const double ALPHA = 0.7;
        out[0] = (float)((ALPHA * S + (1.0 - ALPHA) * M) / D);
    }
}

extern "C" void kernel_launch(void* const* d_in, const int* in_sizes, int n_in,
                              void* d_out, int out_size, void* d_ws, size_t ws_size,
                              hipStream_t stream) {
    const float* logp       = (const float*)d_in[0];
    const float* mask       = (const float*)d_in[1];
    const float* sim_values = (const float*)d_in[2];
    const float* idf_values = (const float*)d_in[3];
    const int*   target     = (const int*)d_in[4];
    const int*   sim_cols   = (const int*)d_in[5];
    float* out = (float*)d_out;
    double* partials = (double*)d_ws;   // 3*NROWS doubles = 192 KB, fully overwritten

    dim3 grid(NROWS / ROWS_PER_BLOCK);  // 2048 blocks
    dim3 block(256);
    wordsmooth_main<<<grid, block, 0, stream>>>(logp, mask, sim_values, idf_values,
                                                target, sim_cols, partials);
    wordsmooth_finalize<<<1, 256, 0, stream>>>(partials, out);
}